// Round 5
// baseline (228.054 us; speedup 1.0000x reference)
//
#include <hip/hip_runtime.h>

// ---------------------------------------------------------------------------
// Net_65798898975283: 2x GraphConv (add-aggr) + 3-layer MLP head + log_softmax
// N=20000 nodes, E=320000 edges, dims 256->128->64->128->64->10
//
// R4 structure (6 dispatches):
//   1 memset        cur[2N] = 0
//   2 prep          weights->bf16 [N][K] transpose + dst histogram
//   3 scan_gemm1    block 0: exclusive scan -> ofs; blocks 1..314: conv1 GEMM
//                   C1A = [x@W1_rel | x@W1_root+b1]  (BM=128,BN=128, bf16 out)
//   4 fill          CSR neighbor fill (atomic cursor)
//   5 conv2_fused   per 128-node tile: gather H1=relu(root+sum rel[nbr]) into
//                   LDS, dual GEMM vs WT2 -> C2A = [H1@W2_rel | H1@W2_root+b2]
//   6 mlp_fused     per 64-node tile: gather H2 into LDS, mlp1, mlp2, head,
//                   log_softmax -> out
// ---------------------------------------------------------------------------

#define NNODES 20000
#define NEDGES 320000

typedef __attribute__((ext_vector_type(8))) short bf16x8;
typedef __attribute__((ext_vector_type(4))) float f32x4;

__device__ inline short f2bf(float f) {
    unsigned u = __builtin_bit_cast(unsigned, f);
    u += 0x7FFFu + ((u >> 16) & 1u);   // RNE (finite inputs)
    return (short)(u >> 16);
}
__device__ inline float bf2f(short h) {
    unsigned u = ((unsigned)(unsigned short)h) << 16;
    return __builtin_bit_cast(float, u);
}

// ---------------- prep: weight transpose->bf16  +  dst histogram -----------
__global__ void prep_kernel(const float* __restrict__ W1r, const float* __restrict__ W1o,
                            const float* __restrict__ W2r, const float* __restrict__ W2o,
                            const float* __restrict__ L1,  const float* __restrict__ L2,
                            short* __restrict__ WT,
                            const int* __restrict__ dst, int* __restrict__ cnt) {
    const int b = blockIdx.x;
    if (b < 384) {
        int idx = b * 256 + threadIdx.x;   // 0..98303
        float v;
        if (idx < 65536) {                       // WT1 [256][256]
            int n = idx >> 8, k = idx & 255;
            v = (n < 128) ? W1r[k * 128 + n] : W1o[k * 128 + (n - 128)];
        } else if (idx < 65536 + 16384) {        // WT2 [128][128]
            int i = idx - 65536;
            int n = i >> 7, k = i & 127;
            v = (n < 64) ? W2r[k * 64 + n] : W2o[k * 64 + (n - 64)];
        } else if (idx < 65536 + 16384 + 8192) { // WT3 [128][64]
            int i = idx - (65536 + 16384);
            int n = i >> 6, k = i & 63;
            v = L1[k * 128 + n];
        } else {                                 // WT4 [64][128]
            int i = idx - (65536 + 16384 + 8192);
            int n = i >> 7, k = i & 127;
            v = L2[k * 64 + n];
        }
        WT[idx] = f2bf(v);
    } else {
        int e = (b - 384) * 256 + threadIdx.x;   // exactly covers NEDGES
        atomicAdd(&cnt[dst[e]], 1);
    }
}

__global__ void fill_kernel(const int* __restrict__ src, const int* __restrict__ dst,
                            const int* __restrict__ ofs, int* __restrict__ cur,
                            int* __restrict__ nbr) {
    int e = blockIdx.x * blockDim.x + threadIdx.x;   // exactly NEDGES threads
    int d = dst[e];
    int p = atomicAdd(&cur[d], 1);
    nbr[ofs[d] + p] = src[e];
}

// ---------------- dispatch 3: block 0 = scan, blocks 1.. = conv1 GEMM -------
// scan: exclusive prefix over cnt[0..n-1] -> ofs[0..n]; 256 thr x chunk 80.
__global__ __launch_bounds__(256)
void scan_gemm1(const int* __restrict__ cnt, int* __restrict__ ofs,
                const float* __restrict__ x, const short* __restrict__ WT1,
                const float* __restrict__ b1, short* __restrict__ C1A, int M) {
    __shared__ short Asl[128][40];
    __shared__ short Bsl[128][40];
    __shared__ int wsum[4];
    const int tid = threadIdx.x;

    if (blockIdx.x == 0) {
        const int n = NNODES;
        const int lane = tid & 63, wid = tid >> 6;
        const int base = tid * 80;
        int s = 0;
        for (int i = 0; i < 80; ++i) {
            int idx = base + i;
            s += (idx < n) ? cnt[idx] : 0;
        }
        int v = s;
        #pragma unroll
        for (int off = 1; off < 64; off <<= 1) {
            int u = __shfl_up(v, off);
            if (lane >= off) v += u;
        }
        if (lane == 63) wsum[wid] = v;
        __syncthreads();
        int wpre = 0;
        for (int w = 0; w < 4; ++w) wpre += (w < wid) ? wsum[w] : 0;
        int run = wpre + (v - s);
        for (int i = 0; i < 80; ++i) {
            int idx = base + i;
            if (idx < n) { ofs[idx] = run; run += cnt[idx]; }
        }
        if (tid == 255) ofs[n] = wpre + v;
        return;
    }

    // ---- conv1 GEMM: BM=128, BN=128, K=256, A fp32->bf16 at staging ----
    const int bidx = blockIdx.x - 1;
    const int bn = (bidx & 1) * 128;
    const int bm = (bidx >> 1) * 128;
    const int wid = tid >> 6, lane = tid & 63;
    const int lr = lane & 15, lg = lane >> 4;
    f32x4 acc[2][8] = {};

    for (int k0 = 0; k0 < 256; k0 += 32) {
        #pragma unroll
        for (int p = 0; p < 4; ++p) {
            int idx = tid + p * 256;          // 0..1023
            int row = idx >> 3;
            int c4 = (idx & 7) * 4;
            int g = bm + row;
            float4 v = make_float4(0.f, 0.f, 0.f, 0.f);
            if (g < M) v = *reinterpret_cast<const float4*>(x + (size_t)g * 256 + k0 + c4);
            short4 h;
            h.x = f2bf(v.x); h.y = f2bf(v.y); h.z = f2bf(v.z); h.w = f2bf(v.w);
            *reinterpret_cast<short4*>(&Asl[row][c4]) = h;
        }
        #pragma unroll
        for (int p = 0; p < 2; ++p) {
            int L = tid + p * 256;            // 0..511
            int n = L >> 2;
            int kc = (L & 3) * 8;
            *reinterpret_cast<bf16x8*>(&Bsl[n][kc]) =
                *reinterpret_cast<const bf16x8*>(WT1 + (size_t)(bn + n) * 256 + k0 + kc);
        }
        __syncthreads();
        bf16x8 a0 = *reinterpret_cast<const bf16x8*>(&Asl[wid * 32 + lr][lg * 8]);
        bf16x8 a1 = *reinterpret_cast<const bf16x8*>(&Asl[wid * 32 + 16 + lr][lg * 8]);
        #pragma unroll
        for (int nt = 0; nt < 8; ++nt) {
            bf16x8 b = *reinterpret_cast<const bf16x8*>(&Bsl[nt * 16 + lr][lg * 8]);
            acc[0][nt] = __builtin_amdgcn_mfma_f32_16x16x32_bf16(a0, b, acc[0][nt], 0, 0, 0);
            acc[1][nt] = __builtin_amdgcn_mfma_f32_16x16x32_bf16(a1, b, acc[1][nt], 0, 0, 0);
        }
        __syncthreads();
    }
    #pragma unroll
    for (int mt = 0; mt < 2; ++mt) {
        #pragma unroll
        for (int r = 0; r < 4; ++r) {
            int row = bm + wid * 32 + mt * 16 + lg * 4 + r;
            if (row >= M) continue;
            #pragma unroll
            for (int nt = 0; nt < 8; ++nt) {
                int col = bn + nt * 16 + lr;
                float v = acc[mt][nt][r];
                if (col >= 128) v += b1[col - 128];
                C1A[(size_t)row * 256 + col] = f2bf(v);
            }
        }
    }
}

// ---------------- dispatch 5: gather H1 (relu) into LDS + conv2 dual GEMM ---
__global__ __launch_bounds__(256)
void conv2_fused(const short* __restrict__ C1A, const short* __restrict__ WT2,
                 const float* __restrict__ b2, const int* __restrict__ ofs,
                 const int* __restrict__ nbr, short* __restrict__ C2A, int M) {
    __shared__ short Asl[128][136];
    __shared__ short Bsl[128][40];
    const int tid = threadIdx.x;
    const int bm = blockIdx.x * 128;

    // gather phase: H1[r,:] = relu(C1A[node,128:] + sum C1A[nbr,0:128])
    #pragma unroll 1
    for (int p = 0; p < 8; ++p) {
        int r = p * 16 + (tid >> 4);
        int node = bm + r;
        int c8 = (tid & 15) * 8;
        float acc[8] = {};
        if (node < M) {
            bf16x8 iv = *reinterpret_cast<const bf16x8*>(C1A + (size_t)node * 256 + 128 + c8);
            #pragma unroll
            for (int i = 0; i < 8; ++i) acc[i] = bf2f(iv[i]);
            const int beg = ofs[node], end = ofs[node + 1];
            for (int j = beg; j < end; ++j) {
                int s = nbr[j];
                bf16x8 vv = *reinterpret_cast<const bf16x8*>(C1A + (size_t)s * 256 + c8);
                #pragma unroll
                for (int i = 0; i < 8; ++i) acc[i] += bf2f(vv[i]);
            }
        }
        bf16x8 o;
        #pragma unroll
        for (int i = 0; i < 8; ++i) o[i] = f2bf(fmaxf(acc[i], 0.f));
        *reinterpret_cast<bf16x8*>(&Asl[r][c8]) = o;
    }
    __syncthreads();

    const int wid = tid >> 6, lane = tid & 63;
    const int lr = lane & 15, lg = lane >> 4;
    f32x4 acc[2][8] = {};
    for (int k0 = 0; k0 < 128; k0 += 32) {
        #pragma unroll
        for (int p = 0; p < 2; ++p) {
            int L = tid + p * 256;
            int n = L >> 2;
            int kc = (L & 3) * 8;
            *reinterpret_cast<bf16x8*>(&Bsl[n][kc]) =
                *reinterpret_cast<const bf16x8*>(WT2 + (size_t)n * 128 + k0 + kc);
        }
        __syncthreads();
        bf16x8 a0 = *reinterpret_cast<const bf16x8*>(&Asl[wid * 32 + lr][k0 + lg * 8]);
        bf16x8 a1 = *reinterpret_cast<const bf16x8*>(&Asl[wid * 32 + 16 + lr][k0 + lg * 8]);
        #pragma unroll
        for (int nt = 0; nt < 8; ++nt) {
            bf16x8 b = *reinterpret_cast<const bf16x8*>(&Bsl[nt * 16 + lr][lg * 8]);
            acc[0][nt] = __builtin_amdgcn_mfma_f32_16x16x32_bf16(a0, b, acc[0][nt], 0, 0, 0);
            acc[1][nt] = __builtin_amdgcn_mfma_f32_16x16x32_bf16(a1, b, acc[1][nt], 0, 0, 0);
        }
        __syncthreads();
    }
    #pragma unroll
    for (int mt = 0; mt < 2; ++mt) {
        #pragma unroll
        for (int r = 0; r < 4; ++r) {
            int row = bm + wid * 32 + mt * 16 + lg * 4 + r;
            if (row >= M) continue;
            #pragma unroll
            for (int nt = 0; nt < 8; ++nt) {
                int col = nt * 16 + lr;
                float v = acc[mt][nt][r];
                if (col >= 64) v += b2[col - 64];
                C2A[(size_t)row * 128 + col] = f2bf(v);
            }
        }
    }
}

// ---------------- dispatch 6: gather H2 + mlp1 + mlp2 + head ----------------
__global__ __launch_bounds__(256)
void mlp_fused(const short* __restrict__ C2A,
               const short* __restrict__ WT3, const float* __restrict__ b3,
               const short* __restrict__ WT4, const float* __restrict__ b4,
               const float* __restrict__ W5, const float* __restrict__ b5,
               const int* __restrict__ ofs, const int* __restrict__ nbr,
               float* __restrict__ out, int M) {
    __shared__ short H2s[64][72];
    __shared__ short H3s[64][136];
    __shared__ short WU[128 * 72];       // WT3 as [128][72], then WT4 as [64][136]
    __shared__ short H4s[64][72];
    __shared__ float cb[842];            // b3[128] b4[64] W5[640] b5[10]
    const int tid = threadIdx.x;
    const int bm = blockIdx.x * 64;
    const int wid = tid >> 6, lane = tid & 63;
    const int lr = lane & 15, lg = lane >> 4;

    // stage consts + WT3
    for (int i = tid; i < 842; i += 256) {
        float v;
        if (i < 128) v = b3[i];
        else if (i < 192) v = b4[i - 128];
        else if (i < 832) v = W5[i - 192];
        else v = b5[i - 832];
        cb[i] = v;
    }
    #pragma unroll
    for (int p = 0; p < 4; ++p) {
        int L = tid + p * 256;           // 0..1023
        int n = L >> 3;
        int kc = (L & 7) * 8;
        *reinterpret_cast<bf16x8*>(&WU[n * 72 + kc]) =
            *reinterpret_cast<const bf16x8*>(WT3 + (size_t)n * 64 + kc);
    }

    // gather phase: H2[r,:] = C2A[node,64:] + sum C2A[nbr,0:64]   (no relu)
    #pragma unroll 1
    for (int p = 0; p < 2; ++p) {
        int r = p * 32 + (tid >> 3);
        int node = bm + r;
        int c8 = (tid & 7) * 8;
        float acc[8] = {};
        if (node < M) {
            bf16x8 iv = *reinterpret_cast<const bf16x8*>(C2A + (size_t)node * 128 + 64 + c8);
            #pragma unroll
            for (int i = 0; i < 8; ++i) acc[i] = bf2f(iv[i]);
            const int beg = ofs[node], end = ofs[node + 1];
            for (int j = beg; j < end; ++j) {
                int s = nbr[j];
                bf16x8 vv = *reinterpret_cast<const bf16x8*>(C2A + (size_t)s * 128 + c8);
                #pragma unroll
                for (int i = 0; i < 8; ++i) acc[i] += bf2f(vv[i]);
            }
        }
        bf16x8 o;
        #pragma unroll
        for (int i = 0; i < 8; ++i) o[i] = f2bf(acc[i]);
        *reinterpret_cast<bf16x8*>(&H2s[r][c8]) = o;
    }
    __syncthreads();

    // mlp1: H3 = relu(H2 @ WT3^T + b3), M=64 N=128 K=64; wave -> 16 rows
    {
        f32x4 a1[8] = {};
        #pragma unroll
        for (int ks = 0; ks < 2; ++ks) {
            bf16x8 a = *reinterpret_cast<const bf16x8*>(&H2s[wid * 16 + lr][ks * 32 + lg * 8]);
            #pragma unroll
            for (int nt = 0; nt < 8; ++nt) {
                bf16x8 b = *reinterpret_cast<const bf16x8*>(&WU[(nt * 16 + lr) * 72 + ks * 32 + lg * 8]);
                a1[nt] = __builtin_amdgcn_mfma_f32_16x16x32_bf16(a, b, a1[nt], 0, 0, 0);
            }
        }
        #pragma unroll
        for (int r = 0; r < 4; ++r) {
            int row = wid * 16 + lg * 4 + r;
            #pragma unroll
            for (int nt = 0; nt < 8; ++nt) {
                int col = nt * 16 + lr;
                float v = fmaxf(a1[nt][r] + cb[col], 0.f);
                H3s[row][col] = f2bf(v);
            }
        }
    }
    __syncthreads();

    // stage WT4 into WU as [64][136]
    #pragma unroll
    for (int p = 0; p < 4; ++p) {
        int L = tid + p * 256;           // 0..1023
        int n = L >> 4;
        int kc = (L & 15) * 8;
        *reinterpret_cast<bf16x8*>(&WU[n * 136 + kc]) =
            *reinterpret_cast<const bf16x8*>(WT4 + (size_t)n * 128 + kc);
    }
    __syncthreads();

    // mlp2: H4 = relu(H3 @ WT4^T + b4), M=64 N=64 K=128
    {
        f32x4 a2[4] = {};
        #pragma unroll
        for (int ks = 0; ks < 4; ++ks) {
            bf16x8 a = *reinterpret_cast<const bf16x8*>(&H3s[wid * 16 + lr][ks * 32 + lg * 8]);
            #pragma unroll
            for (int nt = 0; nt < 4; ++nt) {
                bf16x8 b = *reinterpret_cast<const bf16x8*>(&WU[(nt * 16 + lr) * 136 + ks * 32 + lg * 8]);
                a2[nt] = __builtin_amdgcn_mfma_f32_16x16x32_bf16(a, b, a2[nt], 0, 0, 0);
            }
        }
        #pragma unroll
        for (int r = 0; r < 4; ++r) {
            int row = wid * 16 + lg * 4 + r;
            #pragma unroll
            for (int nt = 0; nt < 4; ++nt) {
                int col = nt * 16 + lr;
                float v = fmaxf(a2[nt][r] + cb[128 + col], 0.f);
                H4s[row][col] = f2bf(v);
            }
        }
    }
    __syncthreads();

    // head: log_softmax(H4 @ W5 + b5) for 64 nodes (threads 0..63)
    if (tid < 64) {
        int node = bm + tid;
        if (node < M) {
            float logit[10];
            #pragma unroll
            for (int c = 0; c < 10; ++c) logit[c] = cb[832 + c];
            #pragma unroll
            for (int k = 0; k < 64; ++k) {
                float hv = bf2f(H4s[tid][k]);
                #pragma unroll
                for (int c = 0; c < 10; ++c) logit[c] += hv * cb[192 + k * 10 + c];
            }
            float m = logit[0];
            #pragma unroll
            for (int c = 1; c < 10; ++c) m = fmaxf(m, logit[c]);
            float s = 0.f;
            #pragma unroll
            for (int c = 0; c < 10; ++c) s += expf(logit[c] - m);
            float lse = m + logf(s);
            float* o = out + (size_t)node * 10;
            #pragma unroll
            for (int c = 0; c < 10; ++c) o[c] = logit[c] - lse;
        }
    }
}

extern "C" void kernel_launch(void* const* d_in, const int* in_sizes, int n_in,
                              void* d_out, int out_size, void* d_ws, size_t ws_size,
                              hipStream_t stream) {
    const float* x       = (const float*)d_in[0];
    const int*   edge    = (const int*)d_in[1];
    const int*   src     = edge;            // edge_index[0]
    const int*   dst     = edge + NEDGES;   // edge_index[1]
    const float* W1_rel  = (const float*)d_in[2];
    const float* W1_root = (const float*)d_in[3];
    const float* b1      = (const float*)d_in[4];
    const float* W2_rel  = (const float*)d_in[5];
    const float* W2_root = (const float*)d_in[6];
    const float* b2      = (const float*)d_in[7];
    const float* lin1_w  = (const float*)d_in[8];
    const float* lin1_b  = (const float*)d_in[9];
    const float* lin2_w  = (const float*)d_in[10];
    const float* lin2_b  = (const float*)d_in[11];
    const float* lin3_w  = (const float*)d_in[12];
    const float* lin3_b  = (const float*)d_in[13];
    float* out = (float*)d_out;

    const int M = NNODES;
    char* p = (char*)d_ws;
    auto alloc = [&](size_t bytes) { char* r = p; p += (bytes + 63) & ~63ull; return r; };
    short* WT  = (short*)alloc(98304 * 2);
    short* WT1 = WT;                 // [256][256]
    short* WT2 = WT1 + 65536;        // [128][128]
    short* WT3 = WT2 + 16384;        // [128][64]
    short* WT4 = WT3 + 8192;         // [64][128]
    short* C1A = (short*)alloc((size_t)M * 256 * 2);
    short* C2A = (short*)alloc((size_t)M * 128 * 2);
    int* ofs = (int*)alloc((NNODES + 1) * 4);
    int* cur = (int*)alloc(2 * NNODES * 4);   // [0:N) hist, [N:2N) fill cursor
    int* nbr = (int*)alloc(NEDGES * 4);

    hipMemsetAsync(cur, 0, 2 * NNODES * sizeof(int), stream);
    prep_kernel<<<384 + NEDGES / 256, 256, 0, stream>>>(
        W1_rel, W1_root, W2_rel, W2_root, lin1_w, lin2_w, WT, dst, cur);
    scan_gemm1<<<1 + 2 * ((M + 127) / 128), 256, 0, stream>>>(
        cur, ofs, x, WT1, b1, C1A, M);
    fill_kernel<<<NEDGES / 256, 256, 0, stream>>>(src, dst, ofs, cur + NNODES, nbr);
    conv2_fused<<<(M + 127) / 128, 256, 0, stream>>>(C1A, WT2, b2, ofs, nbr, C2A, M);
    mlp_fused<<<(M + 63) / 64, 256, 0, stream>>>(C2A, WT3, lin1_b, WT4, lin2_b,
                                                 lin3_w, lin3_b, ofs, nbr, out, M);
}

// Round 6
// 129.659 us; speedup vs baseline: 1.7589x; 1.7589x over previous
//
#include <hip/hip_runtime.h>

// ---------------------------------------------------------------------------
// Net_65798898975283: 2x GraphConv (add-aggr) + 3-layer MLP head + log_softmax
// N=20000 nodes, E=320000 edges, dims 256->128->64->128->64->10
//
// R5 (8 dispatches) — lesson from R4: gathers are latency-bound and need max
// grid parallelism; never serialize them inside a 157-block GEMM kernel.
//   1 memset        cur[2N] = 0
//   2 prep          weights->bf16 [N][K] transpose + dst histogram
//   3 scan_gemm1    block 0: scan -> ofs; blocks 1..: conv1 GEMM BM=128,BN=128
//                   C1A = [x@W1_rel | x@W1_root+b1]
//   4 fill          CSR neighbor fill
//   5 gather1       1250 blocks, 16 lanes/node, 4-way unrolled; H1 = relu(...)
//   6 gemm2         C2A = [H1@W2_rel | H1@W2_root+b2]  (BM=128, BN=128)
//   7 gather2       625 blocks, 8 lanes/node, 4-way unrolled; H2 (no relu)
//   8 mlp_head      per 64-node tile: H2(global)->LDS, mlp1, mlp2, head -> out
// ---------------------------------------------------------------------------

#define NNODES 20000
#define NEDGES 320000

typedef __attribute__((ext_vector_type(8))) short bf16x8;
typedef __attribute__((ext_vector_type(4))) float f32x4;

__device__ inline short f2bf(float f) {
    unsigned u = __builtin_bit_cast(unsigned, f);
    u += 0x7FFFu + ((u >> 16) & 1u);   // RNE (finite inputs)
    return (short)(u >> 16);
}
__device__ inline float bf2f(short h) {
    unsigned u = ((unsigned)(unsigned short)h) << 16;
    return __builtin_bit_cast(float, u);
}

// ---------------- prep: weight transpose->bf16  +  dst histogram -----------
__global__ void prep_kernel(const float* __restrict__ W1r, const float* __restrict__ W1o,
                            const float* __restrict__ W2r, const float* __restrict__ W2o,
                            const float* __restrict__ L1,  const float* __restrict__ L2,
                            short* __restrict__ WT,
                            const int* __restrict__ dst, int* __restrict__ cnt) {
    const int b = blockIdx.x;
    if (b < 384) {
        int idx = b * 256 + threadIdx.x;   // 0..98303
        float v;
        if (idx < 65536) {                       // WT1 [256][256]
            int n = idx >> 8, k = idx & 255;
            v = (n < 128) ? W1r[k * 128 + n] : W1o[k * 128 + (n - 128)];
        } else if (idx < 65536 + 16384) {        // WT2 [128][128]
            int i = idx - 65536;
            int n = i >> 7, k = i & 127;
            v = (n < 64) ? W2r[k * 64 + n] : W2o[k * 64 + (n - 64)];
        } else if (idx < 65536 + 16384 + 8192) { // WT3 [128][64]
            int i = idx - (65536 + 16384);
            int n = i >> 6, k = i & 63;
            v = L1[k * 128 + n];
        } else {                                 // WT4 [64][128]
            int i = idx - (65536 + 16384 + 8192);
            int n = i >> 7, k = i & 127;
            v = L2[k * 64 + n];
        }
        WT[idx] = f2bf(v);
    } else {
        int e = (b - 384) * 256 + threadIdx.x;   // exactly covers NEDGES
        atomicAdd(&cnt[dst[e]], 1);
    }
}

__global__ void fill_kernel(const int* __restrict__ src, const int* __restrict__ dst,
                            const int* __restrict__ ofs, int* __restrict__ cur,
                            int* __restrict__ nbr) {
    int e = blockIdx.x * blockDim.x + threadIdx.x;   // exactly NEDGES threads
    int d = dst[e];
    int p = atomicAdd(&cur[d], 1);
    nbr[ofs[d] + p] = src[e];
}

// ---------------- dispatch 3: block 0 = scan, blocks 1.. = conv1 GEMM -------
__global__ __launch_bounds__(256)
void scan_gemm1(const int* __restrict__ cnt, int* __restrict__ ofs,
                const float* __restrict__ x, const short* __restrict__ WT1,
                const float* __restrict__ b1, short* __restrict__ C1A, int M) {
    __shared__ short Asl[128][40];
    __shared__ short Bsl[128][40];
    __shared__ int wsum[4];
    const int tid = threadIdx.x;

    if (blockIdx.x == 0) {
        const int n = NNODES;
        const int lane = tid & 63, wid4 = tid >> 6;
        const int base = tid * 80;
        int s = 0;
        for (int i = 0; i < 80; ++i) {
            int idx = base + i;
            s += (idx < n) ? cnt[idx] : 0;
        }
        int v = s;
        #pragma unroll
        for (int off = 1; off < 64; off <<= 1) {
            int u = __shfl_up(v, off);
            if (lane >= off) v += u;
        }
        if (lane == 63) wsum[wid4] = v;
        __syncthreads();
        int wpre = 0;
        for (int w = 0; w < 4; ++w) wpre += (w < wid4) ? wsum[w] : 0;
        int run = wpre + (v - s);
        for (int i = 0; i < 80; ++i) {
            int idx = base + i;
            if (idx < n) { ofs[idx] = run; run += cnt[idx]; }
        }
        if (tid == 255) ofs[n] = wpre + v;
        return;
    }

    const int bidx = blockIdx.x - 1;
    const int bn = (bidx & 1) * 128;
    const int bm = (bidx >> 1) * 128;
    const int wid = tid >> 6, lane = tid & 63;
    const int lr = lane & 15, lg = lane >> 4;
    f32x4 acc[2][8] = {};

    for (int k0 = 0; k0 < 256; k0 += 32) {
        #pragma unroll
        for (int p = 0; p < 4; ++p) {
            int idx = tid + p * 256;          // 0..1023
            int row = idx >> 3;
            int c4 = (idx & 7) * 4;
            int g = bm + row;
            float4 v = make_float4(0.f, 0.f, 0.f, 0.f);
            if (g < M) v = *reinterpret_cast<const float4*>(x + (size_t)g * 256 + k0 + c4);
            short4 h;
            h.x = f2bf(v.x); h.y = f2bf(v.y); h.z = f2bf(v.z); h.w = f2bf(v.w);
            *reinterpret_cast<short4*>(&Asl[row][c4]) = h;
        }
        #pragma unroll
        for (int p = 0; p < 2; ++p) {
            int L = tid + p * 256;            // 0..511
            int n = L >> 2;
            int kc = (L & 3) * 8;
            *reinterpret_cast<bf16x8*>(&Bsl[n][kc]) =
                *reinterpret_cast<const bf16x8*>(WT1 + (size_t)(bn + n) * 256 + k0 + kc);
        }
        __syncthreads();
        bf16x8 a0 = *reinterpret_cast<const bf16x8*>(&Asl[wid * 32 + lr][lg * 8]);
        bf16x8 a1 = *reinterpret_cast<const bf16x8*>(&Asl[wid * 32 + 16 + lr][lg * 8]);
        #pragma unroll
        for (int nt = 0; nt < 8; ++nt) {
            bf16x8 b = *reinterpret_cast<const bf16x8*>(&Bsl[nt * 16 + lr][lg * 8]);
            acc[0][nt] = __builtin_amdgcn_mfma_f32_16x16x32_bf16(a0, b, acc[0][nt], 0, 0, 0);
            acc[1][nt] = __builtin_amdgcn_mfma_f32_16x16x32_bf16(a1, b, acc[1][nt], 0, 0, 0);
        }
        __syncthreads();
    }
    #pragma unroll
    for (int mt = 0; mt < 2; ++mt) {
        #pragma unroll
        for (int r = 0; r < 4; ++r) {
            int row = bm + wid * 32 + mt * 16 + lg * 4 + r;
            if (row >= M) continue;
            #pragma unroll
            for (int nt = 0; nt < 8; ++nt) {
                int col = bn + nt * 16 + lr;
                float v = acc[mt][nt][r];
                if (col >= 128) v += b1[col - 128];
                C1A[(size_t)row * 256 + col] = f2bf(v);
            }
        }
    }
}

// ---------------- gather: out = opt_relu(init + sum rel[nbr]); 4-way unroll -
// GPN lanes/node, 16B loads; rel/init columns inside a row of stride ld.
template<int GPN, int LD, int RELOFF, int INITOFF, bool RELU>
__global__ void gather_bf16(const short* __restrict__ base,
                            const int* __restrict__ ofs, const int* __restrict__ nbr,
                            short* __restrict__ outp, int ldo) {
    const int tid = threadIdx.x;
    const int node = blockIdx.x * (256 / GPN) + tid / GPN;
    const int c8 = (tid % GPN) * 8;
    float acc[8];
    bf16x8 iv = *reinterpret_cast<const bf16x8*>(base + (size_t)node * LD + INITOFF + c8);
    #pragma unroll
    for (int i = 0; i < 8; ++i) acc[i] = bf2f(iv[i]);
    const int beg = ofs[node], end = ofs[node + 1];
    int j = beg;
    for (; j + 3 < end; j += 4) {
        int s0 = nbr[j], s1 = nbr[j + 1], s2 = nbr[j + 2], s3 = nbr[j + 3];
        bf16x8 v0 = *reinterpret_cast<const bf16x8*>(base + (size_t)s0 * LD + RELOFF + c8);
        bf16x8 v1 = *reinterpret_cast<const bf16x8*>(base + (size_t)s1 * LD + RELOFF + c8);
        bf16x8 v2 = *reinterpret_cast<const bf16x8*>(base + (size_t)s2 * LD + RELOFF + c8);
        bf16x8 v3 = *reinterpret_cast<const bf16x8*>(base + (size_t)s3 * LD + RELOFF + c8);
        #pragma unroll
        for (int i = 0; i < 8; ++i)
            acc[i] += (bf2f(v0[i]) + bf2f(v1[i])) + (bf2f(v2[i]) + bf2f(v3[i]));
    }
    for (; j < end; ++j) {
        int s = nbr[j];
        bf16x8 vv = *reinterpret_cast<const bf16x8*>(base + (size_t)s * LD + RELOFF + c8);
        #pragma unroll
        for (int i = 0; i < 8; ++i) acc[i] += bf2f(vv[i]);
    }
    bf16x8 o;
    #pragma unroll
    for (int i = 0; i < 8; ++i) {
        float vo = RELU ? fmaxf(acc[i], 0.f) : acc[i];
        o[i] = f2bf(vo);
    }
    *reinterpret_cast<bf16x8*>(outp + (size_t)node * ldo + c8) = o;
}

// ---------------- gemm2: C2A = [H1@W2_rel | H1@W2_root+b2] ------------------
// BM=128, BN=128, K=128; A bf16 [M][128].
__global__ __launch_bounds__(256)
void gemm2(const short* __restrict__ H1, const short* __restrict__ WT2,
           const float* __restrict__ b2, short* __restrict__ C2A, int M) {
    __shared__ short Asl[128][40];
    __shared__ short Bsl[128][40];
    const int tid = threadIdx.x;
    const int bm = blockIdx.x * 128;
    const int wid = tid >> 6, lane = tid & 63;
    const int lr = lane & 15, lg = lane >> 4;
    f32x4 acc[2][8] = {};
    for (int k0 = 0; k0 < 128; k0 += 32) {
        #pragma unroll
        for (int p = 0; p < 2; ++p) {
            int L = tid + p * 256;        // 0..511
            int row = L >> 2;
            int cc = (L & 3) * 8;
            int g = bm + row;
            bf16x8 v = {};
            if (g < M) v = *reinterpret_cast<const bf16x8*>(H1 + (size_t)g * 128 + k0 + cc);
            *reinterpret_cast<bf16x8*>(&Asl[row][cc]) = v;
        }
        #pragma unroll
        for (int p = 0; p < 2; ++p) {
            int L = tid + p * 256;
            int n = L >> 2;
            int kc = (L & 3) * 8;
            *reinterpret_cast<bf16x8*>(&Bsl[n][kc]) =
                *reinterpret_cast<const bf16x8*>(WT2 + (size_t)n * 128 + k0 + kc);
        }
        __syncthreads();
        bf16x8 a0 = *reinterpret_cast<const bf16x8*>(&Asl[wid * 32 + lr][lg * 8]);
        bf16x8 a1 = *reinterpret_cast<const bf16x8*>(&Asl[wid * 32 + 16 + lr][lg * 8]);
        #pragma unroll
        for (int nt = 0; nt < 8; ++nt) {
            bf16x8 b = *reinterpret_cast<const bf16x8*>(&Bsl[nt * 16 + lr][lg * 8]);
            acc[0][nt] = __builtin_amdgcn_mfma_f32_16x16x32_bf16(a0, b, acc[0][nt], 0, 0, 0);
            acc[1][nt] = __builtin_amdgcn_mfma_f32_16x16x32_bf16(a1, b, acc[1][nt], 0, 0, 0);
        }
        __syncthreads();
    }
    #pragma unroll
    for (int mt = 0; mt < 2; ++mt) {
        #pragma unroll
        for (int r = 0; r < 4; ++r) {
            int row = bm + wid * 32 + mt * 16 + lg * 4 + r;
            if (row >= M) continue;
            #pragma unroll
            for (int nt = 0; nt < 8; ++nt) {
                int col = nt * 16 + lr;
                float v = acc[mt][nt][r];
                if (col >= 64) v += b2[col - 64];
                C2A[(size_t)row * 128 + col] = f2bf(v);
            }
        }
    }
}

// ---------------- mlp_head: H2(global) -> mlp1 -> mlp2 -> head -> out -------
__global__ __launch_bounds__(256)
void mlp_head(const short* __restrict__ H2,
              const short* __restrict__ WT3, const float* __restrict__ b3,
              const short* __restrict__ WT4, const float* __restrict__ b4,
              const float* __restrict__ W5, const float* __restrict__ b5,
              float* __restrict__ out, int M) {
    __shared__ short H2s[64][72];
    __shared__ short H3s[64][136];
    __shared__ short WU[128 * 72];       // WT3 as [128][72], then WT4 as [64][136]
    __shared__ short H4s[64][72];
    __shared__ float cb[842];            // b3[128] b4[64] W5[640] b5[10]
    const int tid = threadIdx.x;
    const int bm = blockIdx.x * 64;
    const int wid = tid >> 6, lane = tid & 63;
    const int lr = lane & 15, lg = lane >> 4;

    for (int i = tid; i < 842; i += 256) {
        float v;
        if (i < 128) v = b3[i];
        else if (i < 192) v = b4[i - 128];
        else if (i < 832) v = W5[i - 192];
        else v = b5[i - 832];
        cb[i] = v;
    }
    #pragma unroll
    for (int p = 0; p < 4; ++p) {
        int L = tid + p * 256;           // 0..1023  (WT3 [128][64])
        int n = L >> 3;
        int kc = (L & 7) * 8;
        *reinterpret_cast<bf16x8*>(&WU[n * 72 + kc]) =
            *reinterpret_cast<const bf16x8*>(WT3 + (size_t)n * 64 + kc);
    }
    // H2 tile -> LDS (sequential)
    #pragma unroll
    for (int p = 0; p < 2; ++p) {
        int L = tid + p * 256;           // 0..511
        int r = L >> 3;
        int c8 = (L & 7) * 8;
        int node = bm + r;
        bf16x8 v = {};
        if (node < M) v = *reinterpret_cast<const bf16x8*>(H2 + (size_t)node * 64 + c8);
        *reinterpret_cast<bf16x8*>(&H2s[r][c8]) = v;
    }
    __syncthreads();

    // mlp1: H3 = relu(H2 @ WT3^T + b3), 64x128, K=64; wave -> 16 rows
    {
        f32x4 a1[8] = {};
        #pragma unroll
        for (int ks = 0; ks < 2; ++ks) {
            bf16x8 a = *reinterpret_cast<const bf16x8*>(&H2s[wid * 16 + lr][ks * 32 + lg * 8]);
            #pragma unroll
            for (int nt = 0; nt < 8; ++nt) {
                bf16x8 b = *reinterpret_cast<const bf16x8*>(&WU[(nt * 16 + lr) * 72 + ks * 32 + lg * 8]);
                a1[nt] = __builtin_amdgcn_mfma_f32_16x16x32_bf16(a, b, a1[nt], 0, 0, 0);
            }
        }
        #pragma unroll
        for (int r = 0; r < 4; ++r) {
            int row = wid * 16 + lg * 4 + r;
            #pragma unroll
            for (int nt = 0; nt < 8; ++nt) {
                int col = nt * 16 + lr;
                H3s[row][col] = f2bf(fmaxf(a1[nt][r] + cb[col], 0.f));
            }
        }
    }
    __syncthreads();

    #pragma unroll
    for (int p = 0; p < 4; ++p) {
        int L = tid + p * 256;           // WT4 [64][128] -> WU stride 136
        int n = L >> 4;
        int kc = (L & 15) * 8;
        *reinterpret_cast<bf16x8*>(&WU[n * 136 + kc]) =
            *reinterpret_cast<const bf16x8*>(WT4 + (size_t)n * 128 + kc);
    }
    __syncthreads();

    // mlp2: H4 = relu(H3 @ WT4^T + b4), 64x64, K=128
    {
        f32x4 a2[4] = {};
        #pragma unroll
        for (int ks = 0; ks < 4; ++ks) {
            bf16x8 a = *reinterpret_cast<const bf16x8*>(&H3s[wid * 16 + lr][ks * 32 + lg * 8]);
            #pragma unroll
            for (int nt = 0; nt < 4; ++nt) {
                bf16x8 b = *reinterpret_cast<const bf16x8*>(&WU[(nt * 16 + lr) * 136 + ks * 32 + lg * 8]);
                a2[nt] = __builtin_amdgcn_mfma_f32_16x16x32_bf16(a, b, a2[nt], 0, 0, 0);
            }
        }
        #pragma unroll
        for (int r = 0; r < 4; ++r) {
            int row = wid * 16 + lg * 4 + r;
            #pragma unroll
            for (int nt = 0; nt < 4; ++nt) {
                int col = nt * 16 + lr;
                H4s[row][col] = f2bf(fmaxf(a2[nt][r] + cb[128 + col], 0.f));
            }
        }
    }
    __syncthreads();

    // head: log_softmax(H4 @ W5 + b5)
    if (tid < 64) {
        int node = bm + tid;
        if (node < M) {
            float logit[10];
            #pragma unroll
            for (int c = 0; c < 10; ++c) logit[c] = cb[832 + c];
            #pragma unroll
            for (int k = 0; k < 64; ++k) {
                float hv = bf2f(H4s[tid][k]);
                #pragma unroll
                for (int c = 0; c < 10; ++c) logit[c] += hv * cb[192 + k * 10 + c];
            }
            float m = logit[0];
            #pragma unroll
            for (int c = 1; c < 10; ++c) m = fmaxf(m, logit[c]);
            float s = 0.f;
            #pragma unroll
            for (int c = 0; c < 10; ++c) s += expf(logit[c] - m);
            float lse = m + logf(s);
            float* o = out + (size_t)node * 10;
            #pragma unroll
            for (int c = 0; c < 10; ++c) o[c] = logit[c] - lse;
        }
    }
}

extern "C" void kernel_launch(void* const* d_in, const int* in_sizes, int n_in,
                              void* d_out, int out_size, void* d_ws, size_t ws_size,
                              hipStream_t stream) {
    const float* x       = (const float*)d_in[0];
    const int*   edge    = (const int*)d_in[1];
    const int*   src     = edge;            // edge_index[0]
    const int*   dst     = edge + NEDGES;   // edge_index[1]
    const float* W1_rel  = (const float*)d_in[2];
    const float* W1_root = (const float*)d_in[3];
    const float* b1      = (const float*)d_in[4];
    const float* W2_rel  = (const float*)d_in[5];
    const float* W2_root = (const float*)d_in[6];
    const float* b2      = (const float*)d_in[7];
    const float* lin1_w  = (const float*)d_in[8];
    const float* lin1_b  = (const float*)d_in[9];
    const float* lin2_w  = (const float*)d_in[10];
    const float* lin2_b  = (const float*)d_in[11];
    const float* lin3_w  = (const float*)d_in[12];
    const float* lin3_b  = (const float*)d_in[13];
    float* out = (float*)d_out;

    const int M = NNODES;
    char* p = (char*)d_ws;
    auto alloc = [&](size_t bytes) { char* r = p; p += (bytes + 63) & ~63ull; return r; };
    short* WT  = (short*)alloc(98304 * 2);
    short* WT1 = WT;                 // [256][256]
    short* WT2 = WT1 + 65536;        // [128][128]
    short* WT3 = WT2 + 16384;        // [128][64]
    short* WT4 = WT3 + 8192;         // [64][128]
    short* C1A = (short*)alloc((size_t)M * 256 * 2);
    short* H1  = (short*)alloc((size_t)M * 128 * 2);
    short* C2A = (short*)alloc((size_t)M * 128 * 2);
    short* H2  = (short*)alloc((size_t)M * 64 * 2);
    int* ofs = (int*)alloc((NNODES + 1) * 4);
    int* cur = (int*)alloc(2 * NNODES * 4);   // [0:N) hist, [N:2N) fill cursor
    int* nbr = (int*)alloc(NEDGES * 4);

    hipMemsetAsync(cur, 0, 2 * NNODES * sizeof(int), stream);
    prep_kernel<<<384 + NEDGES / 256, 256, 0, stream>>>(
        W1_rel, W1_root, W2_rel, W2_root, lin1_w, lin2_w, WT, dst, cur);
    scan_gemm1<<<1 + 2 * ((M + 127) / 128), 256, 0, stream>>>(
        cur, ofs, x, WT1, b1, C1A, M);
    fill_kernel<<<NEDGES / 256, 256, 0, stream>>>(src, dst, ofs, cur + NNODES, nbr);

    // gather1: H1 = relu(C1A[:,128:] + sum C1A[nbr,0:128]); 16 lanes/node
    gather_bf16<16, 256, 0, 128, true><<<NNODES / 16, 256, 0, stream>>>(
        C1A, ofs, nbr, H1, 128);
    gemm2<<<(M + 127) / 128, 256, 0, stream>>>(H1, WT2, b2, C2A, M);
    // gather2: H2 = C2A[:,64:] + sum C2A[nbr,0:64]; 8 lanes/node
    gather_bf16<8, 128, 0, 64, false><<<NNODES / 32, 256, 0, stream>>>(
        C2A, ofs, nbr, H2, 64);
    mlp_head<<<(M + 63) / 64, 256, 0, stream>>>(H2, WT3, lin1_b, WT4, lin2_b,
                                                lin3_w, lin3_b, out, M);
}